// Round 3
// baseline (12956.465 us; speedup 1.0000x reference)
//
#include <hip/hip_runtime.h>
#include <cstdint>
#include <cstddef>

#define NB   32     // batch
#define NTT  2048   // time steps
#define NIN  256    // input size
#define NH   256    // hidden
#define NG   32     // workgroups
#define BLOCK 256

typedef __attribute__((ext_vector_type(8))) short    s8v;
typedef __attribute__((ext_vector_type(4))) float    f4v;
typedef __attribute__((ext_vector_type(4))) unsigned u4v;
typedef __attribute__((ext_vector_type(2))) unsigned u2v;

__device__ __forceinline__ float u2f(unsigned u) {
    union { float f; unsigned u; } x; x.u = u; return x.f;
}
__device__ __forceinline__ unsigned cvt_pk_bf16(float s0, float s1) {
    unsigned r;
    asm("v_cvt_pk_bf16_f32 %0, %1, %2" : "=v"(r) : "v"(s0), "v"(s1));
    return r;  // lo16 = bf16(s0), hi16 = bf16(s1)
}
__device__ __forceinline__ void split2(float v0, float v1, unsigned& hp, unsigned& lp) {
    hp = cvt_pk_bf16(v0, v1);
    float h0 = u2f(hp << 16);
    float h1 = u2f(hp & 0xFFFF0000u);
    lp = cvt_pk_bf16(v0 - h0, v1 - h1);  // lo compensates hi rounding exactly in fp32
}
__device__ __forceinline__ void split8(f4v a, f4v b, u4v& hw, u4v& lw) {
    unsigned h0,h1,h2,h3,l0,l1,l2,l3;
    split2(a[0], a[1], h0, l0);
    split2(a[2], a[3], h1, l1);
    split2(b[0], b[1], h2, l2);
    split2(b[2], b[3], h3, l3);
    hw = (u4v){h0,h1,h2,h3};
    lw = (u4v){l0,l1,l2,l3};
}

// ---- coherent h-message loads: 8 x dwordx2, each 8B atom = (packed, tag) ----
template<int OFF>
__device__ __forceinline__ void coh_ld2x8(const unsigned long long* base,
        u2v& a0, u2v& a1, u2v& a2, u2v& a3, u2v& a4, u2v& a5, u2v& a6, u2v& a7) {
    asm volatile(
        "global_load_dwordx2 %0, %8, off offset:%c9  sc0 sc1\n\t"
        "global_load_dwordx2 %1, %8, off offset:%c10 sc0 sc1\n\t"
        "global_load_dwordx2 %2, %8, off offset:%c11 sc0 sc1\n\t"
        "global_load_dwordx2 %3, %8, off offset:%c12 sc0 sc1\n\t"
        "global_load_dwordx2 %4, %8, off offset:%c13 sc0 sc1\n\t"
        "global_load_dwordx2 %5, %8, off offset:%c14 sc0 sc1\n\t"
        "global_load_dwordx2 %6, %8, off offset:%c15 sc0 sc1\n\t"
        "global_load_dwordx2 %7, %8, off offset:%c16 sc0 sc1"
        : "=&v"(a0), "=&v"(a1), "=&v"(a2), "=&v"(a3),
          "=&v"(a4), "=&v"(a5), "=&v"(a6), "=&v"(a7)
        : "v"(base), "n"(OFF), "n"(OFF+8), "n"(OFF+16), "n"(OFF+24),
          "n"(OFF+32), "n"(OFF+40), "n"(OFF+48), "n"(OFF+56)
        : "memory");
}
// ---- plain x prefetch: 2 x dwordx4 ----
template<int OFF>
__device__ __forceinline__ void pf_ld4x2(const float* base, f4v& a, f4v& b) {
    asm volatile(
        "global_load_dwordx4 %0, %2, off offset:%c3\n\t"
        "global_load_dwordx4 %1, %2, off offset:%c4"
        : "=&v"(a), "=&v"(b)
        : "v"(base), "n"(OFF), "n"(OFF+16)
        : "memory");
}
__device__ __forceinline__ void coh_store2(unsigned long long* p, unsigned lo, unsigned hi) {
    u2v v; v[0] = lo; v[1] = hi;
    asm volatile("global_store_dwordx2 %0, %1, off sc0 sc1" :: "v"(p), "v"(v) : "memory");
}

__device__ __forceinline__ float fast_sig(float v) {
    const float L2E = 1.4426950408889634f;
    return __builtin_amdgcn_rcpf(1.f + __builtin_amdgcn_exp2f(-L2E * v));
}
__device__ __forceinline__ float fast_tanh(float v) {
    const float L2E2 = 2.8853900817779268f;
    float e = __builtin_amdgcn_exp2f(L2E2 * v);
    return 1.f - 2.f * __builtin_amdgcn_rcpf(e + 1.f);
}

// A LDS tile: [32 rows][512 bf16] hi/lo planes; 16B-chunk XOR swizzle:
// chunk kc (0..63) of row r lives at byte r*1024 + ((kc ^ (r&7)) << 4).
// Chunks 0..31 = x-part (k 0..255), 32..63 = h-part (k 256..511).

#define ISSUE_H()                                                                              \
    do {                                                                                       \
        coh_ld2x8<0>(hb, hw_[0][0],hw_[0][1],hw_[0][2],hw_[0][3],                              \
                         hw_[0][4],hw_[0][5],hw_[0][6],hw_[0][7]);                             \
        coh_ld2x8<512>(hb, hw_[1][0],hw_[1][1],hw_[1][2],hw_[1][3],                            \
                           hw_[1][4],hw_[1][5],hw_[1][6],hw_[1][7]);                           \
        coh_ld2x8<1024>(hb, hw_[2][0],hw_[2][1],hw_[2][2],hw_[2][3],                           \
                            hw_[2][4],hw_[2][5],hw_[2][6],hw_[2][7]);                          \
        coh_ld2x8<1536>(hb, hw_[3][0],hw_[3][1],hw_[3][2],hw_[3][3],                           \
                            hw_[3][4],hw_[3][5],hw_[3][6],hw_[3][7]);                          \
    } while (0)

__global__ __launch_bounds__(BLOCK, 1) void lstm_kernel(
    const float* __restrict__ x,
    const float* __restrict__ Wf, const float* __restrict__ bfp,
    const float* __restrict__ Wi, const float* __restrict__ bip,
    const float* __restrict__ Wo, const float* __restrict__ bop,
    const float* __restrict__ Wc, const float* __restrict__ bcp,
    float* __restrict__ out,
    unsigned long long* __restrict__ hbuf)   // [2][32][256] atoms (packed, tag)
{
    __shared__ unsigned short Ahi[NB * 512];
    __shared__ unsigned short Alo[NB * 512];
    __shared__ float zbuf[32][35];           // padded: write 2-way max, read <=3-way

    char* AhiB = (char*)Ahi;
    char* AloB = (char*)Alo;

    const int wg   = blockIdx.x;
    const int tid  = threadIdx.x;
    const int lane = tid & 63;
    const int wv   = tid >> 6;

    // ---------- init: stage this WG's weight slice transposed+split into LDS ----------
    {
        const int lc   = tid >> 3;                 // local z-col 0..31 (gate*8 + lh)
        const int gate = lc >> 3;
        const int col  = wg * 8 + (lc & 7);
        const float* W = (gate == 0) ? Wf : (gate == 1) ? Wi : (gate == 2) ? Wo : Wc;
        const int c0   = (tid & 7) * 8;
        #pragma unroll
        for (int cj = 0; cj < 8; ++cj) {
            const int kc = c0 + cj;
            const int k0 = kc * 8;
            f4v a, b;
            #pragma unroll
            for (int e = 0; e < 4; ++e) a[e] = W[(size_t)(k0 + e) * NH + col];
            #pragma unroll
            for (int e = 0; e < 4; ++e) b[e] = W[(size_t)(k0 + 4 + e) * NH + col];
            u4v hwv, lwv;
            split8(a, b, hwv, lwv);
            *(u4v*)(AhiB + lc * 1024 + ((kc ^ (lc & 7)) << 4)) = hwv;
            *(u4v*)(AloB + lc * 1024 + ((kc ^ (lc & 7)) << 4)) = lwv;
        }
    }
    __syncthreads();

    const int mt = wv & 1;   // M-tile (batch rows mt*16..)
    const int nt = wv >> 1;  // N-tile (z-cols nt*16..)

    // ---------- persistent register-resident B fragments (hi+lo) ----------
    s8v bhi[16], blo[16];
    {
        const int brow = nt * 16 + (lane & 15);
        const int bsub = lane >> 4;
        #pragma unroll
        for (int kt = 0; kt < 16; ++kt) {
            const int kc = kt * 4 + bsub;
            bhi[kt] = *(s8v*)(AhiB + brow * 1024 + ((kc ^ (brow & 7)) << 4));
            blo[kt] = *(s8v*)(AloB + brow * 1024 + ((kc ^ (brow & 7)) << 4));
        }
    }
    __syncthreads();

    // update role: thread = (batch ub, local h-col ulh)
    const int ub   = tid >> 3;
    const int ulh  = tid & 7;
    const int ucol = wg * 8 + ulh;
    const float bias_f = bfp[ucol];
    const float bias_i = bip[ucol];
    const float bias_o = bop[ucol];
    const float bias_c = bcp[ucol];
    float cst = 0.f;

    // staging role: thread = (row sb, segment sseg); handles chunks j*8+sseg
    const int sb   = tid >> 3;
    const int sseg = tid & 7;

    const int arow = mt * 16 + (lane & 15);
    const int asub = lane >> 4;

    // prologue: x for t=0 (plain loads; compiler inserts waits)
    f4v xa[4], xb[4];
    {
        const float* xr = x + (size_t)sb * NTT * NIN + sseg * 8;
        #pragma unroll
        for (int j = 0; j < 4; ++j) {
            xa[j] = *(const f4v*)(xr + j * 64);
            xb[j] = *(const f4v*)(xr + j * 64 + 4);
        }
    }

    for (int t = 0; t < NTT; ++t) {
        // ---- S0: x prefetch (issued last iter, 8 loads) done; allow 2 pending stores
        asm volatile("s_waitcnt vmcnt(2)" ::: "memory");
        __builtin_amdgcn_sched_barrier(0);

        const unsigned texp = (unsigned)t;
        const unsigned long long* hb =
            hbuf + (size_t)(t & 1) * (NB * NH) + sb * NH + sseg * 8;
        u2v hw_[4][8];

        // ---- S1: issue speculative h-message loads (32 x dwordx2, coherent)
        if (t > 0) ISSUE_H();

        // ---- S2: stage x-part into LDS from prefetched regs
        #pragma unroll
        for (int j = 0; j < 4; ++j) {
            u4v hwv, lwv;
            split8(xa[j], xb[j], hwv, lwv);
            const int kc = j * 8 + sseg;
            *(u4v*)(AhiB + sb * 1024 + ((kc ^ (sb & 7)) << 4)) = hwv;
            *(u4v*)(AloB + sb * 1024 + ((kc ^ (sb & 7)) << 4)) = lwv;
        }

        // ---- S3: issue x prefetch for t+1 (8 loads, stays in flight past S6)
        {
            const int tp = (t < NTT - 1) ? t + 1 : t;
            const float* xr = x + ((size_t)sb * NTT + tp) * NIN + sseg * 8;
            pf_ld4x2<0>(xr, xa[0], xb[0]);
            pf_ld4x2<256>(xr, xa[1], xb[1]);
            pf_ld4x2<512>(xr, xa[2], xb[2]);
            pf_ld4x2<768>(xr, xa[3], xb[3]);
        }

        __syncthreads();   // B1: x-part staged

        // ---- S5: MFMA x-part (k 0..255) — overlaps h-load latency
        f4v acc0 = (f4v){0.f, 0.f, 0.f, 0.f};
        f4v acc1 = acc0, acc2 = acc0;
        #pragma unroll
        for (int kt = 0; kt < 8; ++kt) {
            const int kc = kt * 4 + asub;
            s8v ah = *(s8v*)(AhiB + arow * 1024 + ((kc ^ (arow & 7)) << 4));
            s8v al = *(s8v*)(AloB + arow * 1024 + ((kc ^ (arow & 7)) << 4));
            acc0 = __builtin_amdgcn_mfma_f32_16x16x32_bf16(ah, bhi[kt], acc0, 0, 0, 0);
            acc1 = __builtin_amdgcn_mfma_f32_16x16x32_bf16(ah, blo[kt], acc1, 0, 0, 0);
            acc2 = __builtin_amdgcn_mfma_f32_16x16x32_bf16(al, bhi[kt], acc2, 0, 0, 0);
        }

        // ---- S6: wait h loads (x prefetch stays in flight), validate tags, retry if stale
        if (t > 0) {
            asm volatile("s_waitcnt vmcnt(8)" ::: "memory");
            __builtin_amdgcn_sched_barrier(0);
            int guard = 0;
            for (;;) {
                unsigned d = 0;
                #pragma unroll
                for (int j = 0; j < 4; ++j)
                    #pragma unroll
                    for (int e = 0; e < 8; ++e)
                        d |= (hw_[j][e][1] ^ texp);
                if (!__any(d != 0)) break;          // all 64 lanes fresh
                if (++guard > (1 << 16)) break;     // fail loud, never hang
                __builtin_amdgcn_s_sleep(1);
                ISSUE_H();
                asm volatile("s_waitcnt vmcnt(0)" ::: "memory");
                __builtin_amdgcn_sched_barrier(0);
            }
            // unpack: packed word = hi | lo<<16; tags at odd dwords
            #pragma unroll
            for (int j = 0; j < 4; ++j) {
                u4v hwv, lwv;
                hwv[0] = __builtin_amdgcn_perm(hw_[j][1][0], hw_[j][0][0], 0x05040100u);
                hwv[1] = __builtin_amdgcn_perm(hw_[j][3][0], hw_[j][2][0], 0x05040100u);
                hwv[2] = __builtin_amdgcn_perm(hw_[j][5][0], hw_[j][4][0], 0x05040100u);
                hwv[3] = __builtin_amdgcn_perm(hw_[j][7][0], hw_[j][6][0], 0x05040100u);
                lwv[0] = __builtin_amdgcn_perm(hw_[j][1][0], hw_[j][0][0], 0x07060302u);
                lwv[1] = __builtin_amdgcn_perm(hw_[j][3][0], hw_[j][2][0], 0x07060302u);
                lwv[2] = __builtin_amdgcn_perm(hw_[j][5][0], hw_[j][4][0], 0x07060302u);
                lwv[3] = __builtin_amdgcn_perm(hw_[j][7][0], hw_[j][6][0], 0x07060302u);
                const int kc = 32 + j * 8 + sseg;
                *(u4v*)(AhiB + sb * 1024 + ((kc ^ (sb & 7)) << 4)) = hwv;
                *(u4v*)(AloB + sb * 1024 + ((kc ^ (sb & 7)) << 4)) = lwv;
            }
        } else {
            const u4v zz = (u4v){0u, 0u, 0u, 0u};
            #pragma unroll
            for (int j = 0; j < 4; ++j) {
                const int kc = 32 + j * 8 + sseg;
                *(u4v*)(AhiB + sb * 1024 + ((kc ^ (sb & 7)) << 4)) = zz;
                *(u4v*)(AloB + sb * 1024 + ((kc ^ (sb & 7)) << 4)) = zz;
            }
        }

        __syncthreads();   // B3: h-part staged

        // ---- S9: MFMA h-part (k 256..511)
        #pragma unroll
        for (int kt = 8; kt < 16; ++kt) {
            const int kc = kt * 4 + asub;
            s8v ah = *(s8v*)(AhiB + arow * 1024 + ((kc ^ (arow & 7)) << 4));
            s8v al = *(s8v*)(AloB + arow * 1024 + ((kc ^ (arow & 7)) << 4));
            acc0 = __builtin_amdgcn_mfma_f32_16x16x32_bf16(ah, bhi[kt], acc0, 0, 0, 0);
            acc1 = __builtin_amdgcn_mfma_f32_16x16x32_bf16(ah, blo[kt], acc1, 0, 0, 0);
            acc2 = __builtin_amdgcn_mfma_f32_16x16x32_bf16(al, bhi[kt], acc2, 0, 0, 0);
        }
        const f4v zv = acc0 + acc1 + acc2;

        // ---- S10: z exchange via dedicated padded zbuf (no extra barrier needed before)
        {
            const int zc = nt * 16 + (lane & 15);
            const int rb = mt * 16 + (lane >> 4) * 4;   // C layout: col=l&15, row=(l>>4)*4+j
            #pragma unroll
            for (int j = 0; j < 4; ++j)
                zbuf[rb + j][zc] = zv[j];
        }
        __syncthreads();   // B5: z visible

        // ---- S12: gates + state update + h publish (single 8B atomic message)
        {
            const float zf = zbuf[ub][ulh]      + bias_f;
            const float zi = zbuf[ub][8 + ulh]  + bias_i;
            const float zo = zbuf[ub][16 + ulh] + bias_o;
            const float zg = zbuf[ub][24 + ulh] + bias_c;
            const float fg = fast_sig(zf);
            const float ig = fast_sig(zi);
            const float og = fast_sig(zo);
            const float gg = fast_tanh(zg);
            cst = fg * cst + ig * gg;
            const float hv = og * fast_tanh(cst);
            // output is reverse-time order; plain cached store
            out[((size_t)ub * NTT + (NTT - 1 - t)) * NH + ucol] = hv;
            // pack hi|lo<<16 and publish with tag t+1 (slot (t+1)&1)
            unsigned p0  = cvt_pk_bf16(hv, 0.f);
            float   hif  = u2f(p0 << 16);
            unsigned w   = cvt_pk_bf16(hv, hv - hif);
            coh_store2(hbuf + (size_t)((t + 1) & 1) * (NB * NH) + ub * NH + ucol,
                       w, (unsigned)(t + 1));
        }
        // no end-of-step barrier: B1 of t+1 orders zbuf/A-tile reuse
    }
}

extern "C" void kernel_launch(void* const* d_in, const int* in_sizes, int n_in,
                              void* d_out, int out_size, void* d_ws, size_t ws_size,
                              hipStream_t stream) {
    (void)in_sizes; (void)n_in; (void)out_size; (void)ws_size;
    const float* x  = (const float*)d_in[0];
    const float* Wf = (const float*)d_in[1];
    const float* bf = (const float*)d_in[2];
    const float* Wi = (const float*)d_in[3];
    const float* bi = (const float*)d_in[4];
    const float* Wo = (const float*)d_in[5];
    const float* bo = (const float*)d_in[6];
    const float* Wc = (const float*)d_in[7];
    const float* bc = (const float*)d_in[8];
    float* out = (float*)d_out;

    unsigned long long* hbuf = (unsigned long long*)d_ws;  // 2*32*256*8B = 128 KiB
    // poison 0xAAAA.. tags never equal any step tag (1..2048) -> safe cold start

    lstm_kernel<<<NG, BLOCK, 0, stream>>>(x, Wf, bf, Wi, bi, Wo, bo, Wc, bc,
                                          out, hbuf);
}

// Round 5
// 7763.001 us; speedup vs baseline: 1.6690x; 1.6690x over previous
//
#include <hip/hip_runtime.h>
#include <cstdint>
#include <cstddef>

#define NB    32     // batch
#define NTT   2048   // time steps
#define NIN   256    // input size
#define NH    256    // hidden
#define NG    16     // workgroups
#define BLOCK 512    // threads per WG (8 waves)
#define NHC   16     // h-cols per WG (z-cols = 64)

typedef __attribute__((ext_vector_type(8))) short    s8v;
typedef __attribute__((ext_vector_type(4))) float    f4v;
typedef __attribute__((ext_vector_type(4))) unsigned u4v;

__device__ __forceinline__ float u2f(unsigned u) {
    union { float f; unsigned u; } x; x.u = u; return x.f;
}
__device__ __forceinline__ unsigned cvt_pk_bf16(float s0, float s1) {
    unsigned r;
    asm("v_cvt_pk_bf16_f32 %0, %1, %2" : "=v"(r) : "v"(s0), "v"(s1));
    return r;  // lo16 = bf16(s0), hi16 = bf16(s1)
}
__device__ __forceinline__ void split2(float v0, float v1, unsigned& hp, unsigned& lp) {
    hp = cvt_pk_bf16(v0, v1);
    float h0 = u2f(hp << 16);
    float h1 = u2f(hp & 0xFFFF0000u);
    lp = cvt_pk_bf16(v0 - h0, v1 - h1);  // lo compensates hi rounding exactly in fp32
}
__device__ __forceinline__ void split8(f4v a, f4v b, u4v& hw, u4v& lw) {
    unsigned h0,h1,h2,h3,l0,l1,l2,l3;
    split2(a[0], a[1], h0, l0);
    split2(a[2], a[3], h1, l1);
    split2(b[0], b[1], h2, l2);
    split2(b[2], b[3], h3, l3);
    hw = (u4v){h0,h1,h2,h3};
    lw = (u4v){l0,l1,l2,l3};
}
__device__ __forceinline__ float fast_sig(float v) {
    const float L2E = 1.4426950408889634f;
    return __builtin_amdgcn_rcpf(1.f + __builtin_amdgcn_exp2f(-L2E * v));
}
__device__ __forceinline__ float fast_tanh(float v) {
    const float L2E2 = 2.8853900817779268f;
    float e = __builtin_amdgcn_exp2f(L2E2 * v);
    return 1.f - 2.f * __builtin_amdgcn_rcpf(e + 1.f);
}

// ---- device-scope (agent) coherent ops: SC[1:0]=10 -> `sc1`.
// Coherence point = Infinity Cache / MALL (shared by all XCDs), cacheable there.
__device__ __forceinline__ u4v ld4_dev(const unsigned* p) {
    u4v v;
    asm volatile("global_load_dwordx4 %0, %1, off sc1" : "=v"(v) : "v"(p));
    return v;  // NOT valid until a subsequent s_waitcnt vmcnt(0)
}
__device__ __forceinline__ int ldf_dev(const int* p) {
    int v;
    asm volatile("global_load_dword %0, %1, off sc1\n\ts_waitcnt vmcnt(0)"
                 : "=v"(v) : "v"(p) : "memory");
    return v;
}
__device__ __forceinline__ void st_dev(unsigned* p, unsigned v) {
    asm volatile("global_store_dword %0, %1, off sc1" :: "v"(p), "v"(v) : "memory");
}
// plain x prefetch: 2 x dwordx4
template<int OFF>
__device__ __forceinline__ void pf_ld4x2(const float* base, f4v& a, f4v& b) {
    asm volatile(
        "global_load_dwordx4 %0, %2, off offset:%c3\n\t"
        "global_load_dwordx4 %1, %2, off offset:%c4"
        : "=&v"(a), "=&v"(b)
        : "v"(base), "n"(OFF), "n"(OFF+16)
        : "memory");
}

// A LDS tile: [32 rows][512 bf16] hi/lo planes; 16B-chunk XOR swizzle:
// chunk kc (0..63) of row r lives at byte r*1024 + ((kc ^ (r&7)) << 4).
// Chunks 0..31 = x-part (k 0..255), 32..63 = h-part (k 256..511).

__global__ __launch_bounds__(BLOCK, 1) void lstm_kernel(
    const float* __restrict__ x,
    const float* __restrict__ Wf, const float* __restrict__ bfp,
    const float* __restrict__ Wi, const float* __restrict__ bip,
    const float* __restrict__ Wo, const float* __restrict__ bop,
    const float* __restrict__ Wc, const float* __restrict__ bcp,
    float* __restrict__ out,
    unsigned* __restrict__ wsbase)
{
    __shared__ unsigned short Ahi[NB * 512];
    __shared__ unsigned short Alo[NB * 512];
    __shared__ float zbuf[32][68];     // 64 z-cols + pad

    char* AhiB = (char*)Ahi;
    char* AloB = (char*)Alo;
    const int wg   = blockIdx.x;
    const int tid  = threadIdx.x;
    const int lane = tid & 63;
    const int wv   = tid >> 6;
    const int mt   = wv & 1;   // M-tile (batch rows mt*16..)
    const int nt   = wv >> 1;  // N-tile 0..3 (16 z-cols each; col group = gate nt)

    int* flags     = (int*)wsbase;     // [16] step flags (memset 0 by launcher)
    unsigned* hbuf = wsbase + 1024;    // [2][32][256] packed h (hi | lo<<16)

    // ---------- weights: 2 passes through LDS -> persistent register B-frags ----------
    // Pass p stages local z-cols [0,32) of this WG's pass tile:
    //   global gate = 2p + (lc>>4), h-col = wg*16 + (lc&15)
    s8v bhi[16], blo[16];
    for (int p = 0; p < 2; ++p) {
        {
            const int lc   = tid >> 4;             // pass-local z-col 0..31
            const int gate = 2 * p + (lc >> 4);
            const int col  = wg * NHC + (lc & 15);
            const float* W = (gate == 0) ? Wf : (gate == 1) ? Wi : (gate == 2) ? Wo : Wc;
            #pragma unroll
            for (int cj = 0; cj < 4; ++cj) {
                const int kc = (tid & 15) * 4 + cj;
                const int k0 = kc * 8;
                f4v a, b;
                #pragma unroll
                for (int e = 0; e < 4; ++e) a[e] = W[(size_t)(k0 + e) * NH + col];
                #pragma unroll
                for (int e = 0; e < 4; ++e) b[e] = W[(size_t)(k0 + 4 + e) * NH + col];
                u4v hwv, lwv;
                split8(a, b, hwv, lwv);
                *(u4v*)(AhiB + lc * 1024 + ((kc ^ (lc & 7)) << 4)) = hwv;
                *(u4v*)(AloB + lc * 1024 + ((kc ^ (lc & 7)) << 4)) = lwv;
            }
        }
        __syncthreads();
        if ((nt >> 1) == p) {
            const int brow = (nt & 1) * 16 + (lane & 15);
            const int bsub = lane >> 4;
            #pragma unroll
            for (int kt = 0; kt < 16; ++kt) {
                const int kc = kt * 4 + bsub;
                bhi[kt] = *(s8v*)(AhiB + brow * 1024 + ((kc ^ (brow & 7)) << 4));
                blo[kt] = *(s8v*)(AloB + brow * 1024 + ((kc ^ (brow & 7)) << 4));
            }
        }
        __syncthreads();
    }

    // update role: thread = (batch ub, local h-col ulh)
    const int ub   = tid >> 4;
    const int ulh  = tid & 15;
    const int ucol = wg * NHC + ulh;
    const float bias_f = bfp[ucol];
    const float bias_i = bip[ucol];
    const float bias_o = bop[ucol];
    const float bias_c = bcp[ucol];
    float cst = 0.f;

    // staging role: thread = (row sb, segment sseg); handles chunks sseg*2+{0,1}
    const int sb   = tid >> 4;
    const int sseg = tid & 15;

    const int arow = mt * 16 + (lane & 15);
    const int asub = lane >> 4;

    // prologue: x for t=0 (plain C loads; compiler inserts waits)
    f4v xv[4];
    {
        const float* xr = x + (size_t)sb * NTT * NIN + sseg * 16;
        xv[0] = *(const f4v*)(xr);
        xv[1] = *(const f4v*)(xr + 4);
        xv[2] = *(const f4v*)(xr + 8);
        xv[3] = *(const f4v*)(xr + 12);
    }

    for (int t = 0; t < NTT; ++t) {
        // ---- S2: stage x-part into LDS from prefetched regs (chunks sseg*2, sseg*2+1)
        #pragma unroll
        for (int j = 0; j < 2; ++j) {
            u4v hwv, lwv;
            split8(xv[2 * j], xv[2 * j + 1], hwv, lwv);
            const int kc = sseg * 2 + j;
            *(u4v*)(AhiB + sb * 1024 + ((kc ^ (sb & 7)) << 4)) = hwv;
            *(u4v*)(AloB + sb * 1024 + ((kc ^ (sb & 7)) << 4)) = lwv;
        }
        // ---- S3: issue x prefetch for t+1 (4 dwordx4, in flight until step-end ack)
        {
            const int tp = (t < NTT - 1) ? t + 1 : t;
            const float* xr = x + ((size_t)sb * NTT + tp) * NIN + sseg * 16;
            pf_ld4x2<0>(xr, xv[0], xv[1]);
            pf_ld4x2<32>(xr, xv[2], xv[3]);
        }
        __syncthreads();   // B1: x-part staged

        // ---- D: wait for all producers of step t-1 (device-scope spin)
        if (t > 0 && wv == 0 && lane < NG) {
            const int* fp = flags + lane;
            int it = 0;
            for (;;) {
                int v = ldf_dev(fp);
                if (!__any(v < t)) break;
                if (++it > 4096) break;    // fail loud, never hang
            }
        }
        __syncthreads();   // B2: flags confirmed for all waves

        f4v acc0 = (f4v){0.f, 0.f, 0.f, 0.f};
        f4v acc1 = acc0, acc2 = acc0;

        if (t > 0) {
            // ---- E-issue: h loads (device scope) BEFORE MFMA-x; RT hides under MFMA
            const unsigned* hp = hbuf + (size_t)(t & 1) * (NB * NH)
                               + (size_t)sb * NH + sseg * 16;
            u4v w0 = ld4_dev(hp);
            u4v w1 = ld4_dev(hp + 4);
            u4v w2 = ld4_dev(hp + 8);
            u4v w3 = ld4_dev(hp + 12);

            // ---- MFMA x-part (k 0..255)
            #pragma unroll
            for (int kt = 0; kt < 8; ++kt) {
                const int kc = kt * 4 + asub;
                s8v ah = *(s8v*)(AhiB + arow * 1024 + ((kc ^ (arow & 7)) << 4));
                s8v al = *(s8v*)(AloB + arow * 1024 + ((kc ^ (arow & 7)) << 4));
                acc0 = __builtin_amdgcn_mfma_f32_16x16x32_bf16(ah, bhi[kt], acc0, 0, 0, 0);
                acc1 = __builtin_amdgcn_mfma_f32_16x16x32_bf16(ah, blo[kt], acc1, 0, 0, 0);
                acc2 = __builtin_amdgcn_mfma_f32_16x16x32_bf16(al, bhi[kt], acc2, 0, 0, 0);
            }

            // ---- E-wait + unpack + stage h chunks (x prefetch also drains here; it's old)
            asm volatile("s_waitcnt vmcnt(0)"
                         : "+v"(w0), "+v"(w1), "+v"(w2), "+v"(w3) :: "memory");
            u4v wA[2][2] = {{w0, w1}, {w2, w3}};
            #pragma unroll
            for (int j = 0; j < 2; ++j) {
                u4v hwv, lwv;
                hwv[0] = __builtin_amdgcn_perm(wA[j][0][1], wA[j][0][0], 0x05040100u);
                hwv[1] = __builtin_amdgcn_perm(wA[j][0][3], wA[j][0][2], 0x05040100u);
                hwv[2] = __builtin_amdgcn_perm(wA[j][1][1], wA[j][1][0], 0x05040100u);
                hwv[3] = __builtin_amdgcn_perm(wA[j][1][3], wA[j][1][2], 0x05040100u);
                lwv[0] = __builtin_amdgcn_perm(wA[j][0][1], wA[j][0][0], 0x07060302u);
                lwv[1] = __builtin_amdgcn_perm(wA[j][0][3], wA[j][0][2], 0x07060302u);
                lwv[2] = __builtin_amdgcn_perm(wA[j][1][1], wA[j][1][0], 0x07060302u);
                lwv[3] = __builtin_amdgcn_perm(wA[j][1][3], wA[j][1][2], 0x07060302u);
                const int kc = 32 + sseg * 2 + j;
                *(u4v*)(AhiB + sb * 1024 + ((kc ^ (sb & 7)) << 4)) = hwv;
                *(u4v*)(AloB + sb * 1024 + ((kc ^ (sb & 7)) << 4)) = lwv;
            }
        } else {
            // t == 0: h = 0
            #pragma unroll
            for (int kt = 0; kt < 8; ++kt) {
                const int kc = kt * 4 + asub;
                s8v ah = *(s8v*)(AhiB + arow * 1024 + ((kc ^ (arow & 7)) << 4));
                s8v al = *(s8v*)(AloB + arow * 1024 + ((kc ^ (arow & 7)) << 4));
                acc0 = __builtin_amdgcn_mfma_f32_16x16x32_bf16(ah, bhi[kt], acc0, 0, 0, 0);
                acc1 = __builtin_amdgcn_mfma_f32_16x16x32_bf16(ah, blo[kt], acc1, 0, 0, 0);
                acc2 = __builtin_amdgcn_mfma_f32_16x16x32_bf16(al, bhi[kt], acc2, 0, 0, 0);
            }
            const u4v zz = (u4v){0u, 0u, 0u, 0u};
            #pragma unroll
            for (int j = 0; j < 2; ++j) {
                const int kc = 32 + sseg * 2 + j;
                *(u4v*)(AhiB + sb * 1024 + ((kc ^ (sb & 7)) << 4)) = zz;
                *(u4v*)(AloB + sb * 1024 + ((kc ^ (sb & 7)) << 4)) = zz;
            }
        }
        __syncthreads();   // B3: h-part staged

        // ---- F: MFMA h-part (k 256..511)
        #pragma unroll
        for (int kt = 8; kt < 16; ++kt) {
            const int kc = kt * 4 + asub;
            s8v ah = *(s8v*)(AhiB + arow * 1024 + ((kc ^ (arow & 7)) << 4));
            s8v al = *(s8v*)(AloB + arow * 1024 + ((kc ^ (arow & 7)) << 4));
            acc0 = __builtin_amdgcn_mfma_f32_16x16x32_bf16(ah, bhi[kt], acc0, 0, 0, 0);
            acc1 = __builtin_amdgcn_mfma_f32_16x16x32_bf16(ah, blo[kt], acc1, 0, 0, 0);
            acc2 = __builtin_amdgcn_mfma_f32_16x16x32_bf16(al, bhi[kt], acc2, 0, 0, 0);
        }
        const f4v zv = acc0 + acc1 + acc2;

        // ---- G: z exchange (zv -> zbuf); C layout: col=l&15, row=(l>>4)*4+j
        {
            const int zc = nt * 16 + (lane & 15);
            const int rb = mt * 16 + (lane >> 4) * 4;
            #pragma unroll
            for (int j = 0; j < 4; ++j)
                zbuf[rb + j][zc] = zv[j];
        }
        __syncthreads();   // B5: z visible

        // ---- H: gates + state update + h publish (device scope)
        {
            const float zf = zbuf[ub][ulh]      + bias_f;
            const float zi = zbuf[ub][16 + ulh] + bias_i;
            const float zo = zbuf[ub][32 + ulh] + bias_o;
            const float zg = zbuf[ub][48 + ulh] + bias_c;
            const float fg = fast_sig(zf);
            const float ig = fast_sig(zi);
            const float og = fast_sig(zo);
            const float gg = fast_tanh(zg);
            cst = fg * cst + ig * gg;
            const float hv = og * fast_tanh(cst);
            // output is reverse-time order; plain cached store
            out[((size_t)ub * NTT + (NTT - 1 - t)) * NH + ucol] = hv;
            // pack hi|lo<<16 and publish into slot (t+1)&1
            unsigned p0  = cvt_pk_bf16(hv, 0.f);
            float   hif  = u2f(p0 << 16);
            unsigned w   = cvt_pk_bf16(hv, hv - hif);
            st_dev(hbuf + (size_t)((t + 1) & 1) * (NB * NH) + (size_t)ub * NH + ucol, w);
        }
        // release: own h stores acked at the coherence point (also pins xv loads
        // so next iteration's S2 reads are dependency-ordered after this wait)
        asm volatile("s_waitcnt vmcnt(0)"
                     : "+v"(xv[0]), "+v"(xv[1]), "+v"(xv[2]), "+v"(xv[3]) :: "memory");
        __syncthreads();   // B6: whole WG's h stores acked
        if (tid == 0)
            st_dev((unsigned*)(flags + wg), (unsigned)(t + 1));
    }
}

extern "C" void kernel_launch(void* const* d_in, const int* in_sizes, int n_in,
                              void* d_out, int out_size, void* d_ws, size_t ws_size,
                              hipStream_t stream) {
    (void)in_sizes; (void)n_in; (void)out_size; (void)ws_size;
    const float* x  = (const float*)d_in[0];
    const float* Wf = (const float*)d_in[1];
    const float* bf = (const float*)d_in[2];
    const float* Wi = (const float*)d_in[3];
    const float* bi = (const float*)d_in[4];
    const float* Wo = (const float*)d_in[5];
    const float* bo = (const float*)d_in[6];
    const float* Wc = (const float*)d_in[7];
    const float* bc = (const float*)d_in[8];
    float* out = (float*)d_out;
    unsigned* ws = (unsigned*)d_ws;

    // zero the flag region (poison 0xAA.. otherwise); hbuf is written before read
    hipMemsetAsync(d_ws, 0, 4096, stream);

    lstm_kernel<<<NG, BLOCK, 0, stream>>>(x, Wf, bf, Wi, bi, Wo, bo, Wc, bc,
                                          out, ws);
}